// Round 14
// baseline (84.872 us; speedup 1.0000x reference)
//
#include <hip/hip_runtime.h>
#include <hip/hip_bf16.h>

#define DIMC 512
#define SEQ 4096
#define M_TOK 16384
#define N_QKV 1536

typedef __bf16 bfv8 __attribute__((ext_vector_type(8)));
typedef float f32v4 __attribute__((ext_vector_type(4)));
typedef unsigned short u16v8 __attribute__((ext_vector_type(8)));

#define VMCNT(n) asm volatile("s_waitcnt vmcnt(" #n ")" ::: "memory")

static __device__ __forceinline__ float bf2f(unsigned short u) {
    union { unsigned int i; float f; } x; x.i = ((unsigned int)u) << 16; return x.f;
}
static __device__ __forceinline__ unsigned short f2bf(float f) {
    union { float f; unsigned int i; } x; x.f = f;
    unsigned int r = x.i + 0x7FFFu + ((x.i >> 16) & 1u);
    return (unsigned short)(r >> 16);
}

static __device__ __forceinline__ void gload_lds16(const void* g, void* s) {
    __builtin_amdgcn_global_load_lds(
        (const __attribute__((address_space(1))) unsigned int*)g,
        (__attribute__((address_space(3))) unsigned int*)s, 16, 0, 0);
}

// ---------------- merged fp32 -> bf16 conversion (x, qkv_w, out_w) ---------
#define NX8  (M_TOK * DIMC / 8)          // 1048576
#define NWQ8 (N_QKV * DIMC / 8)          // 98304
#define NWO8 (DIMC * DIMC / 8)           // 32768
__global__ __launch_bounds__(256) void cvt_all(
    const float* __restrict__ x,  const float* __restrict__ wq,
    const float* __restrict__ wo, unsigned short* __restrict__ xb,
    unsigned short* __restrict__ wqb, unsigned short* __restrict__ wob)
{
    int i = blockIdx.x * 256 + threadIdx.x;
    const float* src; unsigned short* dst; int off;
    if (i < NX8)             { src = x;  dst = xb;  off = i; }
    else if (i < NX8 + NWQ8) { src = wq; dst = wqb; off = i - NX8; }
    else                     { src = wo; dst = wob; off = i - NX8 - NWQ8; }
    const float4* p = (const float4*)src + (size_t)off * 2;
    float4 a = p[0], b = p[1];
    u16v8 o;
    o[0] = f2bf(a.x); o[1] = f2bf(a.y); o[2] = f2bf(a.z); o[3] = f2bf(a.w);
    o[4] = f2bf(b.x); o[5] = f2bf(b.y); o[6] = f2bf(b.z); o[7] = f2bf(b.w);
    *(u16v8*)(dst + (size_t)off * 8) = o;
}

// ---- qkv GEMM: 128x384 tile, BK=32, ring-2 2-phase, EXACT-FIT 512 blocks --
// C[M][N] = A[M][K]*B[N][K]^T + bias. 512 thr / 8 waves (2Mx4N), 64x96/wave.
// R14 theory: R13's grid (128,6)=768 blocks at 2/CU = 1.5 residency rounds
// (measured OccupancyPercent 27% = full round + half-empty tail). 128x384 ->
// grid (128,4)=512 blocks = exactly 2/CU, ALL co-resident, zero tail.
// Ring-2 + R6-proven 2-phase schedule (STAGE(t+1) before compute(t), one
// __syncthreads per tile); LDS 2x(8KB A + 24KB B) = 64KB -> 2 blocks/CU.
// 24 MFMA per barrier (vs 16), 10 ds_reads (0.42 reads/MFMA vs 0.50).
// Swizzle e ^= ((row>>1)&3)<<3 both-sides (0 conflicts, R6-R13).
__global__ __launch_bounds__(512) void gemm_qkv_384(
    const unsigned short* __restrict__ A,  // [M][K] bf16
    const unsigned short* __restrict__ B,  // [N][K] bf16
    const float* __restrict__ bias,        // [N]
    unsigned short* __restrict__ Cout,     // [M][N] bf16
    int M, int N, int K)
{
    __shared__ __align__(16) unsigned short As[2][128 * 32];   // 16KB
    __shared__ __align__(16) unsigned short Bs[2][384 * 32];   // 48KB
    const int tid  = threadIdx.x;
    const int lane = tid & 63;
    const int wid  = tid >> 6;       // 0..7
    const int wm   = wid >> 2;       // 0..1 -> rows [wm*64,+64)
    const int wn   = wid & 3;        // 0..3 -> cols [wn*96,+96)
    const int m0 = blockIdx.x * 128;
    const int n0 = blockIdx.y * 384;
    const int frow = lane & 15;
    const int fcol = (lane >> 4) * 8;
    const int NT = K >> 5;           // 16 K-tiles

    f32v4 acc[4][6] = {};

    // staging (inverse-swizzled global source, rule 21)
    const int arow = tid >> 2;
    const int acol = ((tid & 3) * 8) ^ (((arow >> 1) & 3) << 3);
    const unsigned short* aSrc = A + (size_t)(m0 + arow) * K + acol;
    const unsigned short* bSrc[3];
    #pragma unroll
    for (int r = 0; r < 3; ++r) {
        const int brow = r * 128 + (tid >> 2);
        const int bcol = ((tid & 3) * 8) ^ (((brow >> 1) & 3) << 3);
        bSrc[r] = B + (size_t)(n0 + brow) * K + bcol;
    }
    const int aDst = wid * 512;            // wave-uniform (+lane*16B by HW)

#define STAGE(kt, buf)                                                         \
    {                                                                          \
        gload_lds16(aSrc + (kt) * 32, &As[buf][aDst]);                         \
        gload_lds16(bSrc[0] + (kt) * 32, &Bs[buf][aDst]);                      \
        gload_lds16(bSrc[1] + (kt) * 32, &Bs[buf][4096 + aDst]);               \
        gload_lds16(bSrc[2] + (kt) * 32, &Bs[buf][8192 + aDst]);               \
    }

    STAGE(0, 0)
    __syncthreads();

    for (int t = 0; t < NT; ++t) {
        const int p = t & 1;
        if (t + 1 < NT) STAGE(t + 1, p ^ 1)
        bfv8 af[4], bf[6];
        #pragma unroll
        for (int i = 0; i < 4; ++i) {
            const int r = wm * 64 + i * 16 + frow;
            af[i] = *(const bfv8*)(&As[p][r * 32 + (fcol ^ (((r >> 1) & 3) << 3))]);
        }
        #pragma unroll
        for (int j = 0; j < 6; ++j) {
            const int r = wn * 96 + j * 16 + frow;
            bf[j] = *(const bfv8*)(&Bs[p][r * 32 + (fcol ^ (((r >> 1) & 3) << 3))]);
        }
        __builtin_amdgcn_s_setprio(1);
        #pragma unroll
        for (int i = 0; i < 4; ++i)
            #pragma unroll
            for (int j = 0; j < 6; ++j)
                acc[i][j] = __builtin_amdgcn_mfma_f32_16x16x32_bf16(
                    af[i], bf[j], acc[i][j], 0, 0, 0);
        __builtin_amdgcn_s_setprio(0);
        __syncthreads();   // t+1 staged & drained; bufs safe to swap (R6)
    }
#undef STAGE

    // epilogue: D row=(lane>>4)*4+r, col=lane&15 (m89-verified, R2..R13)
    const int erow = (lane >> 4) * 4;
    const int ecol = lane & 15;
    #pragma unroll
    for (int j = 0; j < 6; ++j) {
        const int col = n0 + wn * 96 + j * 16 + ecol;
        const float bv = bias[col];
        #pragma unroll
        for (int i = 0; i < 4; ++i) {
            const int rbase = m0 + wm * 64 + i * 16 + erow;
            #pragma unroll
            for (int r = 0; r < 4; ++r)
                Cout[(size_t)(rbase + r) * N + col] = f2bf(acc[i][j][r] + bv);
        }
    }
}

// ---- out GEMM: NT MFMA, 128x256 block, BK=32, ring-3 (R8/R13-proven) ------
// grid (128,2) = 256 blocks = exact 1/CU, no tail.
__global__ __launch_bounds__(512) void gemm_nt_r3(
    const unsigned short* __restrict__ A,  // [M][K] bf16
    const unsigned short* __restrict__ B,  // [N][K] bf16
    const float* __restrict__ bias,        // [N]
    float* __restrict__ Cout,              // [M][N] f32
    int M, int N, int K)
{
    __shared__ __align__(16) unsigned short As[3][128 * 32];
    __shared__ __align__(16) unsigned short Bs[3][256 * 32];
    const int tid  = threadIdx.x;
    const int lane = tid & 63;
    const int wid  = tid >> 6;
    const int wm   = wid >> 2;
    const int wn   = wid & 3;
    const int m0 = blockIdx.x * 128;
    const int n0 = blockIdx.y * 256;
    const int frow = lane & 15;
    const int fcol = (lane >> 4) * 8;
    const int NT = K >> 5;

    f32v4 acc[4][4] = {};

    const int arow = tid >> 2;
    const int acol = ((tid & 3) * 8) ^ (((arow >> 1) & 3) << 3);
    const unsigned short* aSrc = A + (size_t)(m0 + arow) * K + acol;
    const unsigned short* bSrc[2];
    #pragma unroll
    for (int r = 0; r < 2; ++r) {
        const int brow = r * 128 + (tid >> 2);
        const int bcol = ((tid & 3) * 8) ^ (((brow >> 1) & 3) << 3);
        bSrc[r] = B + (size_t)(n0 + brow) * K + bcol;
    }
    const int aDst = wid * 512;

#define STAGE(kt, slot)                                                        \
    {                                                                          \
        gload_lds16(aSrc + (kt) * 32, &As[slot][aDst]);                        \
        gload_lds16(bSrc[0] + (kt) * 32, &Bs[slot][aDst]);                     \
        gload_lds16(bSrc[1] + (kt) * 32, &Bs[slot][4096 + aDst]);              \
    }

    STAGE(0, 0)
    STAGE(1, 1)
    VMCNT(3);
    __builtin_amdgcn_s_barrier();

    for (int t = 0; t < NT; ++t) {
        const int slot = t % 3;
        bfv8 af[4], bf[4];
        #pragma unroll
        for (int i = 0; i < 4; ++i) {
            const int r = wm * 64 + i * 16 + frow;
            af[i] = *(const bfv8*)(&As[slot][r * 32 + (fcol ^ (((r >> 1) & 3) << 3))]);
        }
        #pragma unroll
        for (int j = 0; j < 4; ++j) {
            const int r = wn * 64 + j * 16 + frow;
            bf[j] = *(const bfv8*)(&Bs[slot][r * 32 + (fcol ^ (((r >> 1) & 3) << 3))]);
        }
        if (t + 2 < NT) STAGE(t + 2, (t + 2) % 3)
        __builtin_amdgcn_s_setprio(1);
        #pragma unroll
        for (int i = 0; i < 4; ++i)
            #pragma unroll
            for (int j = 0; j < 4; ++j)
                acc[i][j] = __builtin_amdgcn_mfma_f32_16x16x32_bf16(
                    af[i], bf[j], acc[i][j], 0, 0, 0);
        __builtin_amdgcn_s_setprio(0);
        if (t + 2 < NT) { VMCNT(3); } else { VMCNT(0); }
        __builtin_amdgcn_s_barrier();
    }
#undef STAGE

    const int erow = (lane >> 4) * 4;
    const int ecol = lane & 15;
    #pragma unroll
    for (int j = 0; j < 4; ++j) {
        const int col = n0 + wn * 64 + j * 16 + ecol;
        const float bv = bias[col];
        #pragma unroll
        for (int i = 0; i < 4; ++i) {
            const int rbase = m0 + wm * 64 + i * 16 + erow;
            #pragma unroll
            for (int r = 0; r < 4; ++r)
                Cout[(size_t)(rbase + r) * N + col] = acc[i][j][r] + bv;
        }
    }
}

// ---------------- per-token 8x8 head-mix attention, LDS-free ----------------
// 16 lanes per token: lane16 = h*2 + half (half = 32-dim split).
// Writes Y2 scrambled: y[b][h*512 + (n>>3)][(n&7)*64 + d].
__global__ __launch_bounds__(256) void attn_mix2(
    const unsigned short* __restrict__ Y1, // [16384][1536] bf16
    unsigned short* __restrict__ Y2)       // [16384][512]  bf16 (scrambled)
{
    const int tid  = threadIdx.x;
    const int tok  = blockIdx.x * 16 + (tid >> 4);
    const int l16  = tid & 15;
    const int h    = l16 >> 1;
    const int half = l16 & 1;
    const unsigned short* qkv = Y1 + (size_t)tok * N_QKV;

    float qf[32];
    #pragma unroll
    for (int c = 0; c < 4; ++c) {
        u16v8 v = *(const u16v8*)(qkv + h * 64 + half * 32 + c * 8);
        #pragma unroll
        for (int j = 0; j < 8; ++j) qf[c * 8 + j] = bf2f(v[j]);
    }
    float sc[8];
    #pragma unroll
    for (int g = 0; g < 8; ++g) {
        const unsigned short* kp = qkv + DIMC + g * 64 + half * 32;
        float a = 0.f;
        #pragma unroll
        for (int c = 0; c < 4; ++c) {
            u16v8 v = *(const u16v8*)(kp + c * 8);
            #pragma unroll
            for (int j = 0; j < 8; ++j) a = fmaf(qf[c * 8 + j], bf2f(v[j]), a);
        }
        a += __shfl_xor(a, 1);       // combine the two 32-dim halves
        sc[g] = a * 0.125f;
    }
    float mx = sc[0];
    #pragma unroll
    for (int g = 1; g < 8; ++g) mx = fmaxf(mx, sc[g]);
    float sum = 0.f;
    #pragma unroll
    for (int g = 0; g < 8; ++g) { sc[g] = __expf(sc[g] - mx); sum += sc[g]; }
    const float inv = 1.f / sum;
    #pragma unroll
    for (int g = 0; g < 8; ++g) sc[g] *= inv;

    float o[32] = {};
    #pragma unroll
    for (int g = 0; g < 8; ++g) {
        const unsigned short* vp = qkv + 2 * DIMC + g * 64 + half * 32;
        #pragma unroll
        for (int c = 0; c < 4; ++c) {
            u16v8 v = *(const u16v8*)(vp + c * 8);
            #pragma unroll
            for (int j = 0; j < 8; ++j) o[c * 8 + j] = fmaf(sc[g], bf2f(v[j]), o[c * 8 + j]);
        }
    }
    const int n = tok & (SEQ - 1);
    const int b = tok >> 12;
    const size_t drow = (size_t)b * SEQ + h * 512 + (n >> 3);
    unsigned short* dst = Y2 + drow * DIMC + ((n & 7) << 6) + half * 32;
    #pragma unroll
    for (int c = 0; c < 4; ++c) {
        u16v8 ov;
        #pragma unroll
        for (int j = 0; j < 8; ++j) ov[j] = f2bf(o[c * 8 + j]);
        *(u16v8*)(dst + c * 8) = ov;
    }
}

extern "C" void kernel_launch(void* const* d_in, const int* in_sizes, int n_in,
                              void* d_out, int out_size, void* d_ws, size_t ws_size,
                              hipStream_t stream) {
    const float* x     = (const float*)d_in[0];
    const float* qkv_w = (const float*)d_in[1];
    const float* qkv_b = (const float*)d_in[2];
    const float* out_w = (const float*)d_in[3];
    const float* out_b = (const float*)d_in[4];
    float* out = (float*)d_out;

    unsigned short* Y1 = (unsigned short*)d_ws;            // 50.3 MB
    unsigned short* Xb = Y1 + (size_t)M_TOK * N_QKV;       // 16.8 MB
    unsigned short* Y2 = Xb;   // overlay: Xb dead before attn_mix2 writes Y2
    unsigned short* Wq = Xb + (size_t)M_TOK * DIMC;
    unsigned short* Wo = Wq + (size_t)N_QKV * DIMC;

    cvt_all<<<(NX8 + NWQ8 + NWO8) / 256, 256, 0, stream>>>(x, qkv_w, out_w, Xb, Wq, Wo);

    gemm_qkv_384<<<dim3(M_TOK / 128, N_QKV / 384), 512, 0, stream>>>(
        Xb, Wq, qkv_b, Y1, M_TOK, N_QKV, DIMC);

    attn_mix2<<<M_TOK / 16, 256, 0, stream>>>(Y1, Y2);

    gemm_nt_r3<<<dim3(M_TOK / 128, DIMC / 256), 512, 0, stream>>>(
        Y2, Wo, out_b, out, M_TOK, DIMC, DIMC);
}

// Round 15
// 81.123 us; speedup vs baseline: 1.0462x; 1.0462x over previous
//
#include <hip/hip_runtime.h>
#include <hip/hip_bf16.h>

#define DIMC 512
#define SEQ 4096
#define M_TOK 16384
#define N_QKV 1536

typedef __bf16 bfv8 __attribute__((ext_vector_type(8)));
typedef float f32v4 __attribute__((ext_vector_type(4)));
typedef unsigned short u16v8 __attribute__((ext_vector_type(8)));

#define VMCNT(n) asm volatile("s_waitcnt vmcnt(" #n ")" ::: "memory")

static __device__ __forceinline__ float bf2f(unsigned short u) {
    union { unsigned int i; float f; } x; x.i = ((unsigned int)u) << 16; return x.f;
}
static __device__ __forceinline__ unsigned short f2bf(float f) {
    union { float f; unsigned int i; } x; x.f = f;
    unsigned int r = x.i + 0x7FFFu + ((x.i >> 16) & 1u);
    return (unsigned short)(r >> 16);
}

static __device__ __forceinline__ void gload_lds16(const void* g, void* s) {
    __builtin_amdgcn_global_load_lds(
        (const __attribute__((address_space(1))) unsigned int*)g,
        (__attribute__((address_space(3))) unsigned int*)s, 16, 0, 0);
}

// ---------------- merged fp32 -> bf16 conversion (x, qkv_w, out_w) ---------
#define NX8  (M_TOK * DIMC / 8)          // 1048576
#define NWQ8 (N_QKV * DIMC / 8)          // 98304
#define NWO8 (DIMC * DIMC / 8)           // 32768
__global__ __launch_bounds__(256) void cvt_all(
    const float* __restrict__ x,  const float* __restrict__ wq,
    const float* __restrict__ wo, unsigned short* __restrict__ xb,
    unsigned short* __restrict__ wqb, unsigned short* __restrict__ wob)
{
    int i = blockIdx.x * 256 + threadIdx.x;
    const float* src; unsigned short* dst; int off;
    if (i < NX8)             { src = x;  dst = xb;  off = i; }
    else if (i < NX8 + NWQ8) { src = wq; dst = wqb; off = i - NX8; }
    else                     { src = wo; dst = wob; off = i - NX8 - NWQ8; }
    const float4* p = (const float4*)src + (size_t)off * 2;
    float4 a = p[0], b = p[1];
    u16v8 o;
    o[0] = f2bf(a.x); o[1] = f2bf(a.y); o[2] = f2bf(a.z); o[3] = f2bf(a.w);
    o[4] = f2bf(b.x); o[5] = f2bf(b.y); o[6] = f2bf(b.z); o[7] = f2bf(b.w);
    *(u16v8*)(dst + (size_t)off * 8) = o;
}

// ---- NT MFMA GEMM, 128x256 block, BK=32, RING-3 LDS + counted vmcnt -------
// C[M][N] = A[M][K]*B[N][K]^T + bias. 512 thr / 8 waves (2Mx4N), 64x64/wave.
// TERMINAL CONFIG (best measured lineage, R8/R13 = 81.1-81.3us total):
// ring-3 LDS, STAGE(t+2) at iter t, counted VMCNT(3) (never 0 until tail),
// one raw s_barrier per K-tile, compiler-scheduled lgkmcnt between ds_read
// and MFMA, setprio around the MFMA cluster, G4 swizzle both-sides
// (SQ_LDS_BANK_CONFLICT == 0 measured R6-R14).
// Measured plateau: qkv 39.6us (MfmaUtil 23.6%) vs floors compute 10.3us /
// BW 15us. Rejected by measurement: 8-phase (R3), BK=64 (R5), occupancy
// (R7), reg-staged A (R9/R10), f32-staged A (R11), lgkm variants (R12/R13),
// exact-fit 384 tile (R14), full fusion (R4).
template<bool OUT_BF16>
__global__ __launch_bounds__(512) void gemm_nt_r3(
    const unsigned short* __restrict__ A,  // [M][K] bf16
    const unsigned short* __restrict__ B,  // [N][K] bf16
    const float* __restrict__ bias,        // [N]
    void* __restrict__ Cout,
    int M, int N, int K)
{
    __shared__ __align__(16) unsigned short As[3][128 * 32];   // 24KB
    __shared__ __align__(16) unsigned short Bs[3][256 * 32];   // 48KB
    const int tid  = threadIdx.x;
    const int lane = tid & 63;
    const int wid  = tid >> 6;       // 0..7
    const int wm   = wid >> 2;       // 0..1 -> rows [wm*64,+64)
    const int wn   = wid & 3;        // 0..3 -> cols [wn*64,+64)
    const int m0 = blockIdx.x * 128;
    const int n0 = blockIdx.y * 256;
    const int frow = lane & 15;
    const int fcol = (lane >> 4) * 8;
    const int NT = K >> 5;           // 16 K-tiles

    f32v4 acc[4][4] = {};

    // staging addresses (inverse-swizzled global source, rule 21)
    const int arow = tid >> 2;
    const int acol = ((tid & 3) * 8) ^ (((arow >> 1) & 3) << 3);
    const unsigned short* aSrc = A + (size_t)(m0 + arow) * K + acol;
    const unsigned short* bSrc[2];
    #pragma unroll
    for (int r = 0; r < 2; ++r) {
        const int brow = r * 128 + (tid >> 2);
        const int bcol = ((tid & 3) * 8) ^ (((brow >> 1) & 3) << 3);
        bSrc[r] = B + (size_t)(n0 + brow) * K + bcol;
    }
    const int aDst = wid * 512;            // wave-uniform (+lane*16B by HW)

#define STAGE(kt, slot)                                                        \
    {                                                                          \
        gload_lds16(aSrc + (kt) * 32, &As[slot][aDst]);                        \
        gload_lds16(bSrc[0] + (kt) * 32, &Bs[slot][aDst]);                     \
        gload_lds16(bSrc[1] + (kt) * 32, &Bs[slot][4096 + aDst]);              \
    }

    STAGE(0, 0)
    STAGE(1, 1)
    VMCNT(3);                      // tile-0 landed (only tile-1's 3 remain)
    __builtin_amdgcn_s_barrier();

    for (int t = 0; t < NT; ++t) {
        const int slot = t % 3;
        bfv8 af[4], bf[4];
        #pragma unroll
        for (int i = 0; i < 4; ++i) {
            const int r = wm * 64 + i * 16 + frow;
            af[i] = *(const bfv8*)(&As[slot][r * 32 + (fcol ^ (((r >> 1) & 3) << 3))]);
        }
        #pragma unroll
        for (int j = 0; j < 4; ++j) {
            const int r = wn * 64 + j * 16 + frow;
            bf[j] = *(const bfv8*)(&Bs[slot][r * 32 + (fcol ^ (((r >> 1) & 3) << 3))]);
        }
        if (t + 2 < NT) {
            const int ws = (t + 2) % 3;
            STAGE(t + 2, ws)
        }
        // no forced lgkm drain: compiler inserts counted lgkmcnt before each
        // consuming MFMA, overlapping read latency with the MFMA cluster.
        __builtin_amdgcn_s_setprio(1);
        #pragma unroll
        for (int i = 0; i < 4; ++i)
            #pragma unroll
            for (int j = 0; j < 4; ++j)
                acc[i][j] = __builtin_amdgcn_mfma_f32_16x16x32_bf16(
                    af[i], bf[j], acc[i][j], 0, 0, 0);
        __builtin_amdgcn_s_setprio(0);
        if (t + 2 < NT) { VMCNT(3); } else { VMCNT(0); }
        __builtin_amdgcn_s_barrier();
    }
#undef STAGE

    // epilogue: D row=(lane>>4)*4+r, col=lane&15 (m89-verified, R2..R13-proven)
    const int erow = (lane >> 4) * 4;
    const int ecol = lane & 15;
    #pragma unroll
    for (int j = 0; j < 4; ++j) {
        const int col = n0 + wn * 64 + j * 16 + ecol;
        const float bv = bias[col];
        #pragma unroll
        for (int i = 0; i < 4; ++i) {
            const int rbase = m0 + wm * 64 + i * 16 + erow;
            #pragma unroll
            for (int r = 0; r < 4; ++r) {
                const float v = acc[i][j][r] + bv;
                if constexpr (OUT_BF16)
                    ((unsigned short*)Cout)[(size_t)(rbase + r) * N + col] = f2bf(v);
                else
                    ((float*)Cout)[(size_t)(rbase + r) * N + col] = v;
            }
        }
    }
}

// ---------------- per-token 8x8 head-mix attention, LDS-free ----------------
// 16 lanes per token: lane16 = h*2 + half (half = 32-dim split).
// Writes Y2 scrambled: y[b][h*512 + (n>>3)][(n&7)*64 + d].
__global__ __launch_bounds__(256) void attn_mix2(
    const unsigned short* __restrict__ Y1, // [16384][1536] bf16
    unsigned short* __restrict__ Y2)       // [16384][512]  bf16 (scrambled)
{
    const int tid  = threadIdx.x;
    const int tok  = blockIdx.x * 16 + (tid >> 4);
    const int l16  = tid & 15;
    const int h    = l16 >> 1;
    const int half = l16 & 1;
    const unsigned short* qkv = Y1 + (size_t)tok * N_QKV;

    float qf[32];
    #pragma unroll
    for (int c = 0; c < 4; ++c) {
        u16v8 v = *(const u16v8*)(qkv + h * 64 + half * 32 + c * 8);
        #pragma unroll
        for (int j = 0; j < 8; ++j) qf[c * 8 + j] = bf2f(v[j]);
    }
    float sc[8];
    #pragma unroll
    for (int g = 0; g < 8; ++g) {
        const unsigned short* kp = qkv + DIMC + g * 64 + half * 32;
        float a = 0.f;
        #pragma unroll
        for (int c = 0; c < 4; ++c) {
            u16v8 v = *(const u16v8*)(kp + c * 8);
            #pragma unroll
            for (int j = 0; j < 8; ++j) a = fmaf(qf[c * 8 + j], bf2f(v[j]), a);
        }
        a += __shfl_xor(a, 1);       // combine the two 32-dim halves
        sc[g] = a * 0.125f;
    }
    float mx = sc[0];
    #pragma unroll
    for (int g = 1; g < 8; ++g) mx = fmaxf(mx, sc[g]);
    float sum = 0.f;
    #pragma unroll
    for (int g = 0; g < 8; ++g) { sc[g] = __expf(sc[g] - mx); sum += sc[g]; }
    const float inv = 1.f / sum;
    #pragma unroll
    for (int g = 0; g < 8; ++g) sc[g] *= inv;

    float o[32] = {};
    #pragma unroll
    for (int g = 0; g < 8; ++g) {
        const unsigned short* vp = qkv + 2 * DIMC + g * 64 + half * 32;
        #pragma unroll
        for (int c = 0; c < 4; ++c) {
            u16v8 v = *(const u16v8*)(vp + c * 8);
            #pragma unroll
            for (int j = 0; j < 8; ++j) o[c * 8 + j] = fmaf(sc[g], bf2f(v[j]), o[c * 8 + j]);
        }
    }
    const int n = tok & (SEQ - 1);
    const int b = tok >> 12;
    const size_t drow = (size_t)b * SEQ + h * 512 + (n >> 3);
    unsigned short* dst = Y2 + drow * DIMC + ((n & 7) << 6) + half * 32;
    #pragma unroll
    for (int c = 0; c < 4; ++c) {
        u16v8 ov;
        #pragma unroll
        for (int j = 0; j < 8; ++j) ov[j] = f2bf(o[c * 8 + j]);
        *(u16v8*)(dst + c * 8) = ov;
    }
}

extern "C" void kernel_launch(void* const* d_in, const int* in_sizes, int n_in,
                              void* d_out, int out_size, void* d_ws, size_t ws_size,
                              hipStream_t stream) {
    const float* x     = (const float*)d_in[0];
    const float* qkv_w = (const float*)d_in[1];
    const float* qkv_b = (const float*)d_in[2];
    const float* out_w = (const float*)d_in[3];
    const float* out_b = (const float*)d_in[4];
    float* out = (float*)d_out;

    unsigned short* Y1 = (unsigned short*)d_ws;            // 50.3 MB
    unsigned short* Xb = Y1 + (size_t)M_TOK * N_QKV;       // 16.8 MB
    unsigned short* Y2 = Xb;   // overlay: Xb dead before attn_mix2 writes Y2
    unsigned short* Wq = Xb + (size_t)M_TOK * DIMC;
    unsigned short* Wo = Wq + (size_t)N_QKV * DIMC;

    cvt_all<<<(NX8 + NWQ8 + NWO8) / 256, 256, 0, stream>>>(x, qkv_w, out_w, Xb, Wq, Wo);

    gemm_nt_r3<true><<<dim3(M_TOK / 128, N_QKV / 256), 512, 0, stream>>>(
        Xb, Wq, qkv_b, Y1, M_TOK, N_QKV, DIMC);

    attn_mix2<<<M_TOK / 16, 256, 0, stream>>>(Y1, Y2);

    gemm_nt_r3<false><<<dim3(M_TOK / 128, DIMC / 256), 512, 0, stream>>>(
        Y2, Wo, out_b, out, M_TOK, DIMC, DIMC);
}